// Round 1
// baseline (155.920 us; speedup 1.0000x reference)
//
#include <hip/hip_runtime.h>

// Problem constants (fixed by the reference): N=262144, D=256, B=512, M=1024.
#define FEAT_D   256
#define MAX_M    1024
#define NSETS    512

// starts[b] = first index i with batch[i] >= b  (batch is sorted ascending).
// Computes starts[0..NSETS] inclusive so counts[b] = starts[b+1]-starts[b].
__global__ void k_starts(const int* __restrict__ batch, int n,
                         int* __restrict__ starts) {
    int b = blockIdx.x * blockDim.x + threadIdx.x;
    if (b > NSETS) return;
    int lo = 0, hi = n;
    while (lo < hi) {
        int mid = (lo + hi) >> 1;
        if (batch[mid] < b) lo = mid + 1; else hi = mid;
    }
    starts[b] = lo;
}

// Gather formulation: one output row (b,m) per 64-lane group; each lane moves
// one float4 (64 * 16B = 1024B = one full D=256 fp32 row). Row is either a
// copy of src[starts[b]+m] (if m < counts[b]) or zeros. Single write pass —
// no separate zero-fill of the 512MB padded tensor.
__global__ void k_gather(const float4* __restrict__ src4,
                         const int* __restrict__ starts,
                         float4* __restrict__ out4) {
    int tid  = blockIdx.x * blockDim.x + threadIdx.x;
    int row  = tid >> 6;        // 64 lanes per output row
    int lane = tid & 63;
    int b = row >> 10;          // row / MAX_M
    int m = row & (MAX_M - 1);
    int s   = starts[b];
    int cnt = starts[b + 1] - s;
    float4 v = make_float4(0.f, 0.f, 0.f, 0.f);
    if (m < cnt) v = src4[(size_t)(s + m) * (FEAT_D / 4) + lane];
    out4[(size_t)row * (FEAT_D / 4) + lane] = v;
}

// Mask written as fp32 1.0/0.0 (bool ref is compared as float by harness).
__global__ void k_mask(const int* __restrict__ starts,
                       float* __restrict__ mask) {
    int row = blockIdx.x * blockDim.x + threadIdx.x;
    int b = row >> 10;
    int m = row & (MAX_M - 1);
    int cnt = starts[b + 1] - starts[b];
    mask[row] = (m < cnt) ? 1.0f : 0.0f;
}

extern "C" void kernel_launch(void* const* d_in, const int* in_sizes, int n_in,
                              void* d_out, int out_size, void* d_ws, size_t ws_size,
                              hipStream_t stream) {
    const float* src  = (const float*)d_in[0];
    const int*   batch = (const int*)d_in[1];   // harness delivers ints as int32
    int n = in_sizes[1];                        // N ragged elements

    int* starts = (int*)d_ws;                   // (NSETS+1) ints

    // 1) segment starts via binary search (513 threads, trivial cost)
    k_starts<<<(NSETS + 1 + 255) / 256, 256, 0, stream>>>(batch, n, starts);

    // 2) padded gather: B*M rows, 4 rows per 256-thread block
    int total_rows = NSETS * MAX_M;             // 524288
    k_gather<<<total_rows / 4, 256, 0, stream>>>(
        (const float4*)src, starts, (float4*)d_out);

    // 3) mask: B*M floats after the padded tensor
    float* mask = (float*)d_out + (size_t)NSETS * MAX_M * FEAT_D;
    k_mask<<<total_rows / 256, 256, 0, stream>>>(starts, mask);
}

// Round 2
// 150.651 us; speedup vs baseline: 1.0350x; 1.0350x over previous
//
#include <hip/hip_runtime.h>

// Problem constants (fixed by the reference): N=262144, D=256, B=512, M=1024.
#define FEAT_D   256
#define MAX_M    1024
#define NSETS    512

typedef float f4 __attribute__((ext_vector_type(4)));

// starts[b] = first index i with batch[i] >= b  (batch is sorted ascending).
// Computes starts[0..NSETS] inclusive so counts[b] = starts[b+1]-starts[b].
__global__ void k_starts(const int* __restrict__ batch, int n,
                         int* __restrict__ starts) {
    int b = blockIdx.x * blockDim.x + threadIdx.x;
    if (b > NSETS) return;
    int lo = 0, hi = n;
    while (lo < hi) {
        int mid = (lo + hi) >> 1;
        if (batch[mid] < b) lo = mid + 1; else hi = mid;
    }
    starts[b] = lo;
}

// Gather formulation: one output row (b,m) per 64-lane group; each lane moves
// one float4 (64 * 16B = 1024B = one full D=256 fp32 row). Row is either a
// copy of src[starts[b]+m] (if m < counts[b]) or zeros. Single write pass.
// All traffic is streaming with zero reuse -> nontemporal hints to avoid
// L2 thrash between the 256MB read stream and 539MB write stream.
// Mask (1.0/0.0 fp32) fused: lane 0 of each row writes it.
__global__ void k_gather(const f4* __restrict__ src4,
                         const int* __restrict__ starts,
                         f4* __restrict__ out4,
                         float* __restrict__ mask) {
    int tid  = blockIdx.x * blockDim.x + threadIdx.x;
    int row  = tid >> 6;        // 64 lanes per output row
    int lane = tid & 63;
    int b = row >> 10;          // row / MAX_M
    int m = row & (MAX_M - 1);
    int s   = starts[b];
    int cnt = starts[b + 1] - s;
    f4 v = (f4)(0.0f);
    bool valid = (m < cnt);
    if (valid)
        v = __builtin_nontemporal_load(&src4[(size_t)(s + m) * (FEAT_D / 4) + lane]);
    __builtin_nontemporal_store(v, &out4[(size_t)row * (FEAT_D / 4) + lane]);
    if (lane == 0)
        __builtin_nontemporal_store(valid ? 1.0f : 0.0f, &mask[row]);
}

extern "C" void kernel_launch(void* const* d_in, const int* in_sizes, int n_in,
                              void* d_out, int out_size, void* d_ws, size_t ws_size,
                              hipStream_t stream) {
    const float* src   = (const float*)d_in[0];
    const int*   batch = (const int*)d_in[1];   // harness delivers ints as int32
    int n = in_sizes[1];                        // N ragged elements

    int* starts = (int*)d_ws;                   // (NSETS+1) ints

    // 1) segment starts via binary search (513 threads, trivial cost)
    k_starts<<<(NSETS + 1 + 255) / 256, 256, 0, stream>>>(batch, n, starts);

    // 2) padded gather + fused mask: B*M rows, 4 rows per 256-thread block
    int total_rows = NSETS * MAX_M;             // 524288
    float* mask = (float*)d_out + (size_t)NSETS * MAX_M * FEAT_D;
    k_gather<<<total_rows / 4, 256, 0, stream>>>(
        (const f4*)src, starts, (f4*)d_out, mask);
}